// Round 7
// baseline (230.512 us; speedup 1.0000x reference)
//
#include <hip/hip_runtime.h>
#include <hip/hip_fp16.h>
#include <math.h>

#define BATCH 8192
#define EMB 128
#define TILE 16
#define NTHREADS 1024
#define NWAVES 16
#define CH 136      // chunk stride in halves: 16 rows * 8 + 8 pad (272B; quads decollide banks)
#define WITS 450    // row-major WIT stride (halves): 900B -> 225 words (odd) -> full bank spread
#define ENT_CAP 4096

// ws half-offsets (dense fp16 weights)
#define OFF_E1W1 0        // 64x256
#define OFF_E1W2 16384    // 64x64
#define OFF_E2W1 20480    // 64x320
#define OFF_E2W2 40960    // 128x64
#define OFF_E3W1 49152    // 64x384
#define OFF_E3W2 73728    // 256x64
#define OFF_DW1  90112    // 64x128
#define OFF_DW2  98304    // 1x64
#define W_DENSE  98368
// candidate region (uint32s, based at ws + W_DENSE):
//   [0..128]   offsets (exclusive prefix; [128] = total)
//   [132 ...]  packed entries (j<<16 | fp16bits(T[o][j])), ragged by o

typedef __attribute__((ext_vector_type(8))) _Float16 v8h;
typedef __attribute__((ext_vector_type(4))) float v4f;

struct Smem {
    _Float16 XB[32 * CH];        // base, chunked MFMA-A layout
    _Float16 W12C[24 * CH];      // w1 chunks 0-7, w2 chunks 8-23 (chunked)
    _Float16 H[8 * CH];          // hidden, chunked
    _Float16 CODE[16 * CH];      // tropical out, chunked
    _Float16 WITrm[TILE * WITS]; // wit row-major for the gather
    unsigned int ent[ENT_CAP];
    unsigned int off[132];
};

// ---------------- prepass: weight cvt + ragged candidate build ----------------
__global__ __launch_bounds__(256) void prep_kernel(
    const float* __restrict__ s0, const float* __restrict__ s1,
    const float* __restrict__ s2, const float* __restrict__ s3,
    const float* __restrict__ s4, const float* __restrict__ s5,
    const float* __restrict__ s6, const float* __restrict__ s7,
    const float* __restrict__ trop, _Float16* __restrict__ ws)
{
    const int b = blockIdx.x;
    if (b < 97) {
        const int idx4 = (b * 256 + (int)threadIdx.x) * 4;
        if (idx4 >= W_DENSE) return;
        const float* src; int off;
        if      (idx4 < OFF_E1W2) { src = s0; off = OFF_E1W1; }
        else if (idx4 < OFF_E2W1) { src = s1; off = OFF_E1W2; }
        else if (idx4 < OFF_E2W2) { src = s2; off = OFF_E2W1; }
        else if (idx4 < OFF_E3W1) { src = s3; off = OFF_E2W2; }
        else if (idx4 < OFF_E3W2) { src = s4; off = OFF_E3W1; }
        else if (idx4 < OFF_DW1)  { src = s5; off = OFF_E3W2; }
        else if (idx4 < OFF_DW2)  { src = s6; off = OFF_DW1;  }
        else                      { src = s7; off = OFF_DW2;  }
        const float4 v = *(const float4*)(src + (idx4 - off));
        _Float16* dst = ws + idx4;
        dst[0] = (_Float16)v.x; dst[1] = (_Float16)v.y;
        dst[2] = (_Float16)v.z; dst[3] = (_Float16)v.w;
    } else {
        __shared__ unsigned int cnt[128];
        __shared__ unsigned int offs[129];
        const int o = threadIdx.x;
        float mn = 1e30f;
        float thr = 0.f;
        if (o < 128) {
            const float* row = trop + (size_t)o * 448;
            for (int j = 0; j < 448; j += 4) {
                const float4 t = *(const float4*)(row + j);
                mn = fminf(mn, fminf(fminf(t.x, t.y), fminf(t.z, t.w)));
            }
            // wit in [0,1] (+ fp16 rounding slack) => only j with
            // T[o,j] <= minT + 1.02 can ever win the min. Exact pruning.
            thr = mn + 1.02f;
            int n = 0;
            for (int j = 0; j < 448; ++j) n += (row[j] <= thr) ? 1 : 0;
            cnt[o] = (unsigned)n;
        }
        __syncthreads();
        if (threadIdx.x == 0) {
            unsigned int s = 0;
            for (int i = 0; i < 128; ++i) { offs[i] = s; s += cnt[i]; }
            offs[128] = s;
        }
        __syncthreads();
        unsigned int* base = (unsigned int*)(ws + W_DENSE);
        if (o < 129) base[o] = offs[o < 128 ? o : 128];
        if (o < 128) {
            const float* row = trop + (size_t)o * 448;
            unsigned int w = 132 + offs[o];
            for (int j = 0; j < 448; ++j) {
                const float t = row[j];
                if (t <= thr && w < 132 + ENT_CAP) {
                    const unsigned short hb =
                        __builtin_bit_cast(unsigned short, (_Float16)t);
                    base[w++] = ((unsigned)j << 16) | hb;
                }
            }
        }
    }
}

// ---------------- MFMA dense layer (M=16 rows) ----------------
// D[m][o] = act(bias[o] + sum_k A[m][k]*W[o][k]). A chunked in LDS
// (A0 first STEPS0 steps, then A1); W row-major [O][K] in global.
template <int K, int STEPS0, int O, int ACT, bool CHUNKW, bool RMW>
__device__ __forceinline__ void dense_mfma(
    const _Float16* __restrict__ Wg, const float* __restrict__ bias,
    const _Float16* A0, const _Float16* A1,
    _Float16* OutC, _Float16* OutRM, int rmbase, int wave, int lane)
{
    constexpr int STEPS = K / 32;
    constexpr int NJOBS = O / 16;
    const int l15 = lane & 15;
    const int quad = lane >> 4;

    for (int nt = wave; nt < NJOBS; nt += NWAVES) {
        v4f c = {0.f, 0.f, 0.f, 0.f};
        const _Float16* wrow = Wg + (size_t)(nt * 16 + l15) * K + quad * 8;
        #pragma unroll
        for (int s = 0; s < STEPS; ++s) {
            const int g = s * 4 + quad;
            const _Float16* asrc = (s < STEPS0)
                ? (A0 + g * CH + l15 * 8)
                : (A1 + (g - STEPS0 * 4) * CH + l15 * 8);
            const v8h a = *(const v8h*)asrc;              // A[m=l15][k=quad*8+j]
            const v8h bfr = *(const v8h*)(wrow + s * 32); // B[n=l15][k=quad*8+j]
            c = __builtin_amdgcn_mfma_f32_16x16x32_f16(a, bfr, c, 0, 0, 0);
        }
        const int o = nt * 16 + l15;                      // C/D col = lane&15
        const float bs = bias[o];
        #pragma unroll
        for (int i = 0; i < 4; ++i) {                     // C/D row = quad*4+reg
            float vv = c[i] + bs;
            if (ACT == 0) vv = fmaxf(vv, 0.f);
            else          vv = 1.f / (1.f + __expf(-vv));
            const int m = quad * 4 + i;
            const _Float16 hv = (_Float16)vv;
            if (CHUNKW) OutC[(o >> 3) * CH + m * 8 + (o & 7)] = hv;
            if (RMW)    OutRM[m * WITS + rmbase + o] = hv;
        }
    }
}

// ---------------- fused forward ----------------
__global__ __launch_bounds__(NTHREADS, 8) void tacit_fused_kernel(
    const int* __restrict__ u, const int* __restrict__ v,
    const float* __restrict__ emb,
    const float* __restrict__ e1_b1, const float* __restrict__ e1_b2,
    const float* __restrict__ e2_b1, const float* __restrict__ e2_b2,
    const float* __restrict__ e3_b1, const float* __restrict__ e3_b2,
    const float* __restrict__ dec_b1, const float* __restrict__ dec_b2,
    const _Float16* __restrict__ ws,
    float* __restrict__ out)
{
    __shared__ Smem S;
    const int tid = threadIdx.x;
    const int lane = tid & 63;
    const int wave = tid >> 6;
    const int row0 = blockIdx.x * TILE;

    // ---- Gather + cvt into chunked XB; stage candidate tables ----
    if (tid < 512) {
        const int row = tid & 15;
        const int kq = tid >> 4;                 // 0..31 (0-15 u, 16-31 v)
        const int node = (kq < 16) ? u[row0 + row] : v[row0 + row];
        const int col = (kq & 15) * 8;
        const float4 f0 = *(const float4*)(emb + (size_t)node * EMB + col);
        const float4 f1 = *(const float4*)(emb + (size_t)node * EMB + col + 4);
        v8h hv;
        hv[0] = (_Float16)f0.x; hv[1] = (_Float16)f0.y;
        hv[2] = (_Float16)f0.z; hv[3] = (_Float16)f0.w;
        hv[4] = (_Float16)f1.x; hv[5] = (_Float16)f1.y;
        hv[6] = (_Float16)f1.z; hv[7] = (_Float16)f1.w;
        *(v8h*)&S.XB[kq * CH + row * 8] = hv;
    }
    {
        const unsigned int* base = (const unsigned int*)(ws + W_DENSE);
        if (tid < 33) *(uint4*)&S.off[tid * 4] = *(const uint4*)(base + tid * 4);
        *(uint4*)&S.ent[tid * 4] = *(const uint4*)(base + 132 + tid * 4);
    }
    __syncthreads();

    // ---- Witness 1 ----
    dense_mfma<256, 8, 64, 0, true, false>(ws + OFF_E1W1, e1_b1, S.XB, nullptr,
                                           S.H, nullptr, 0, wave, lane);
    __syncthreads();
    dense_mfma<64, 2, 64, 1, true, true>(ws + OFF_E1W2, e1_b2, S.H, nullptr,
                                         S.W12C, S.WITrm, 0, wave, lane);
    __syncthreads();

    // ---- Witness 2 ----
    dense_mfma<320, 8, 64, 0, true, false>(ws + OFF_E2W1, e2_b1, S.XB, S.W12C,
                                           S.H, nullptr, 0, wave, lane);
    __syncthreads();
    dense_mfma<64, 2, 128, 1, true, true>(ws + OFF_E2W2, e2_b2, S.H, nullptr,
                                          S.W12C + 8 * CH, S.WITrm, 64, wave, lane);
    __syncthreads();

    // ---- Witness 3 ----
    dense_mfma<384, 8, 64, 0, true, false>(ws + OFF_E3W1, e3_b1, S.XB, S.W12C + 8 * CH,
                                           S.H, nullptr, 0, wave, lane);
    __syncthreads();
    dense_mfma<64, 2, 256, 1, false, true>(ws + OFF_E3W2, e3_b2, S.H, nullptr,
                                           nullptr, S.WITrm, 192, wave, lane);
    __syncthreads();

    // ---- Tropical via exact ragged candidate pruning ----
    // wave covers o-octet; lane = (r = lane&15, cp = lane>>4). fp32 sums.
    {
        const int r = lane & 15;
        const int cp = lane >> 4;
        const _Float16* wrow = &S.WITrm[r * WITS];
        #pragma unroll
        for (int i = 0; i < 8; ++i) {
            const int o = (wave << 3) + i;
            const int beg = (int)S.off[o];
            const int end = (int)S.off[o + 1];
            float acc = 1e30f;
            for (int idx = beg + cp; idx < end; idx += 4) {
                const unsigned int cwv = S.ent[idx];
                const int j = (int)(cwv >> 16);
                const float tv = (float)__builtin_bit_cast(
                    _Float16, (unsigned short)(cwv & 0xffffu));
                acc = fminf(acc, (float)wrow[j] + tv);
            }
            acc = fminf(acc, __shfl_xor(acc, 16, 64));
            acc = fminf(acc, __shfl_xor(acc, 32, 64));
            if (cp == 0)
                S.CODE[(o >> 3) * CH + r * 8 + (o & 7)] = (_Float16)acc;
        }
    }
    __syncthreads();

    // ---- Decoder 1: CODE(128) -> H(64) relu ----
    dense_mfma<128, 4, 64, 0, true, false>(ws + OFF_DW1, dec_b1, S.CODE, nullptr,
                                           S.H, nullptr, 0, wave, lane);
    __syncthreads();

    // ---- Decoder 2: H(64) -> scalar ----
    if (tid < TILE) {
        const int r = tid;
        float s = dec_b2[0];
        const _Float16* w2 = ws + OFF_DW2;
        #pragma unroll
        for (int c = 0; c < 8; ++c) {
            const v8h hr = *(const v8h*)(&S.H[c * CH + r * 8]);
            const v8h wr = *(const v8h*)(w2 + c * 8);
            #pragma unroll
            for (int t = 0; t < 8; ++t) s += (float)hr[t] * (float)wr[t];
        }
        out[row0 + r] = s;
    }
}

extern "C" void kernel_launch(void* const* d_in, const int* in_sizes, int n_in,
                              void* d_out, int out_size, void* d_ws, size_t ws_size,
                              hipStream_t stream) {
    const int*   u      = (const int*)d_in[0];
    const int*   v      = (const int*)d_in[1];
    const float* emb    = (const float*)d_in[2];
    const float* e1_w1  = (const float*)d_in[3];
    const float* e1_b1  = (const float*)d_in[4];
    const float* e1_w2  = (const float*)d_in[5];
    const float* e1_b2  = (const float*)d_in[6];
    const float* e2_w1  = (const float*)d_in[7];
    const float* e2_b1  = (const float*)d_in[8];
    const float* e2_w2  = (const float*)d_in[9];
    const float* e2_b2  = (const float*)d_in[10];
    const float* e3_w1  = (const float*)d_in[11];
    const float* e3_b1  = (const float*)d_in[12];
    const float* e3_w2  = (const float*)d_in[13];
    const float* e3_b2  = (const float*)d_in[14];
    const float* trop_w = (const float*)d_in[15];
    const float* dec_w1 = (const float*)d_in[16];
    const float* dec_b1 = (const float*)d_in[17];
    const float* dec_w2 = (const float*)d_in[18];
    const float* dec_b2 = (const float*)d_in[19];
    float* out = (float*)d_out;
    _Float16* ws = (_Float16*)d_ws;

    prep_kernel<<<98, 256, 0, stream>>>(
        e1_w1, e1_w2, e2_w1, e2_w2, e3_w1, e3_w2, dec_w1, dec_w2, trop_w, ws);

    tacit_fused_kernel<<<BATCH / TILE, NTHREADS, 0, stream>>>(
        u, v, emb,
        e1_b1, e1_b2, e2_b1, e2_b2, e3_b1, e3_b2, dec_b1, dec_b2,
        ws, out);
}

// Round 8
// 157.554 us; speedup vs baseline: 1.4631x; 1.4631x over previous
//
#include <hip/hip_runtime.h>
#include <hip/hip_fp16.h>
#include <math.h>

#define BATCH 8192
#define EMB 128
#define TILE 16
#define NTHREADS 1024
#define NWAVES 16
#define CH 136      // chunk stride in halves: 16 rows * 8 + 8 pad (272B; quads decollide banks)
#define WITS 450    // row-major WIT stride (halves): 900B -> 225 words (odd) -> full bank spread
#define ENT_CAP 4096

// ws half-offsets (dense fp16 weights)
#define OFF_E1W1 0        // 64x256
#define OFF_E1W2 16384    // 64x64
#define OFF_E2W1 20480    // 64x320
#define OFF_E2W2 40960    // 128x64
#define OFF_E3W1 49152    // 64x384
#define OFF_E3W2 73728    // 256x64
#define OFF_DW1  90112    // 64x128
#define OFF_DW2  98304    // 1x64
#define W_DENSE  98368
// candidate region (uint32s, based at ws + W_DENSE):
//   [0..128]   offsets (exclusive prefix; [128] = total)
//   [132 ...]  packed entries (j<<16 | fp16bits(T[o][j])), ragged by o

typedef __attribute__((ext_vector_type(8))) _Float16 v8h;
typedef __attribute__((ext_vector_type(4))) float v4f;

struct Smem {
    _Float16 XB[32 * CH];        // base, chunked MFMA-A layout
    _Float16 W12C[24 * CH];      // w1 chunks 0-7, w2 chunks 8-23 (chunked)
    _Float16 H[8 * CH];          // hidden, chunked
    _Float16 CODE[16 * CH];      // tropical out, chunked
    _Float16 WITrm[TILE * WITS]; // wit row-major for the gather
    unsigned int ent[ENT_CAP];
    unsigned int off[132];
};

// ---------------- prepass: weight cvt + ragged candidate build ----------------
// Blocks 0..24: fp32->fp16 cvt (1024-wide). Block 25: wave-parallel candidate
// build — one wave per trop row, lanes scan 7 strided elems, ballot compaction.
__global__ __launch_bounds__(1024) void prep_kernel(
    const float* __restrict__ s0, const float* __restrict__ s1,
    const float* __restrict__ s2, const float* __restrict__ s3,
    const float* __restrict__ s4, const float* __restrict__ s5,
    const float* __restrict__ s6, const float* __restrict__ s7,
    const float* __restrict__ trop, _Float16* __restrict__ ws)
{
    const int b = blockIdx.x;
    const int tid = threadIdx.x;
    if (b < 25) {
        const int idx4 = (b * 1024 + tid) * 4;
        if (idx4 >= W_DENSE) return;
        const float* src; int off;
        if      (idx4 < OFF_E1W2) { src = s0; off = OFF_E1W1; }
        else if (idx4 < OFF_E2W1) { src = s1; off = OFF_E1W2; }
        else if (idx4 < OFF_E2W2) { src = s2; off = OFF_E2W1; }
        else if (idx4 < OFF_E3W1) { src = s3; off = OFF_E2W2; }
        else if (idx4 < OFF_E3W2) { src = s4; off = OFF_E3W1; }
        else if (idx4 < OFF_DW1)  { src = s5; off = OFF_E3W2; }
        else if (idx4 < OFF_DW2)  { src = s6; off = OFF_DW1;  }
        else                      { src = s7; off = OFF_DW2;  }
        const float4 v = *(const float4*)(src + (idx4 - off));
        _Float16* dst = ws + idx4;
        dst[0] = (_Float16)v.x; dst[1] = (_Float16)v.y;
        dst[2] = (_Float16)v.z; dst[3] = (_Float16)v.w;
    } else {
        __shared__ float thrs[128];
        __shared__ unsigned int cnt[128];
        __shared__ unsigned int offs[129];
        const int lane = tid & 63;
        const int wave = tid >> 6;

        // Phase 1: per-row min + count. wit in [0,1] (+fp16 slack) => only
        // j with T[o,j] <= minT + 1.02 can win the min-plus. Exact pruning.
        for (int o = wave; o < 128; o += 16) {
            const float* row = trop + (size_t)o * 448;
            float vals[7];
            float mn = 1e30f;
            #pragma unroll
            for (int it = 0; it < 7; ++it) {
                vals[it] = row[lane + it * 64];
                mn = fminf(mn, vals[it]);
            }
            mn = fminf(mn, __shfl_xor(mn, 1, 64));
            mn = fminf(mn, __shfl_xor(mn, 2, 64));
            mn = fminf(mn, __shfl_xor(mn, 4, 64));
            mn = fminf(mn, __shfl_xor(mn, 8, 64));
            mn = fminf(mn, __shfl_xor(mn, 16, 64));
            mn = fminf(mn, __shfl_xor(mn, 32, 64));
            const float thr = mn + 1.02f;
            int n = 0;
            #pragma unroll
            for (int it = 0; it < 7; ++it)
                n += __popcll(__ballot(vals[it] <= thr));
            if (lane == 0) { thrs[o] = thr; cnt[o] = (unsigned)n; }
        }
        __syncthreads();

        // Phase 2: prefix over 128 counts (tiny, LDS-resident).
        if (tid == 0) {
            unsigned int s = 0;
            for (int i = 0; i < 128; ++i) { offs[i] = s; s += cnt[i]; }
            offs[128] = s;
        }
        __syncthreads();

        unsigned int* base = (unsigned int*)(ws + W_DENSE);
        if (tid < 129) base[tid] = offs[tid];

        // Phase 3: ballot-compacted emission (intra-row order irrelevant
        // for a min-reduction).
        for (int o = wave; o < 128; o += 16) {
            const float* row = trop + (size_t)o * 448;
            const float thr = thrs[o];
            unsigned int done = offs[o];
            #pragma unroll
            for (int it = 0; it < 7; ++it) {
                const int j = lane + it * 64;
                const float t = row[j];
                const bool p = (t <= thr);
                const unsigned long long m = __ballot(p);
                if (p) {
                    const unsigned int pos =
                        done + (unsigned)__popcll(m & ((1ull << lane) - 1ull));
                    if (pos < ENT_CAP) {
                        const unsigned short hb =
                            __builtin_bit_cast(unsigned short, (_Float16)t);
                        base[132 + pos] = ((unsigned)j << 16) | hb;
                    }
                }
                done += (unsigned)__popcll(m);
            }
        }
    }
}

// ---------------- MFMA dense layer (M=16 rows) ----------------
// D[m][o] = act(bias[o] + sum_k A[m][k]*W[o][k]). A chunked in LDS
// (A0 first STEPS0 steps, then A1); W row-major [O][K] in global.
template <int K, int STEPS0, int O, int ACT, bool CHUNKW, bool RMW>
__device__ __forceinline__ void dense_mfma(
    const _Float16* __restrict__ Wg, const float* __restrict__ bias,
    const _Float16* A0, const _Float16* A1,
    _Float16* OutC, _Float16* OutRM, int rmbase, int wave, int lane)
{
    constexpr int STEPS = K / 32;
    constexpr int NJOBS = O / 16;
    const int l15 = lane & 15;
    const int quad = lane >> 4;

    for (int nt = wave; nt < NJOBS; nt += NWAVES) {
        v4f c = {0.f, 0.f, 0.f, 0.f};
        const _Float16* wrow = Wg + (size_t)(nt * 16 + l15) * K + quad * 8;
        #pragma unroll
        for (int s = 0; s < STEPS; ++s) {
            const int g = s * 4 + quad;
            const _Float16* asrc = (s < STEPS0)
                ? (A0 + g * CH + l15 * 8)
                : (A1 + (g - STEPS0 * 4) * CH + l15 * 8);
            const v8h a = *(const v8h*)asrc;              // A[m=l15][k=quad*8+j]
            const v8h bfr = *(const v8h*)(wrow + s * 32); // B[n=l15][k=quad*8+j]
            c = __builtin_amdgcn_mfma_f32_16x16x32_f16(a, bfr, c, 0, 0, 0);
        }
        const int o = nt * 16 + l15;                      // C/D col = lane&15
        const float bs = bias[o];
        #pragma unroll
        for (int i = 0; i < 4; ++i) {                     // C/D row = quad*4+reg
            float vv = c[i] + bs;
            if (ACT == 0) vv = fmaxf(vv, 0.f);
            else          vv = 1.f / (1.f + __expf(-vv));
            const int m = quad * 4 + i;
            const _Float16 hv = (_Float16)vv;
            if (CHUNKW) OutC[(o >> 3) * CH + m * 8 + (o & 7)] = hv;
            if (RMW)    OutRM[m * WITS + rmbase + o] = hv;
        }
    }
}

// ---------------- fused forward ----------------
__global__ __launch_bounds__(NTHREADS, 8) void tacit_fused_kernel(
    const int* __restrict__ u, const int* __restrict__ v,
    const float* __restrict__ emb,
    const float* __restrict__ e1_b1, const float* __restrict__ e1_b2,
    const float* __restrict__ e2_b1, const float* __restrict__ e2_b2,
    const float* __restrict__ e3_b1, const float* __restrict__ e3_b2,
    const float* __restrict__ dec_b1, const float* __restrict__ dec_b2,
    const _Float16* __restrict__ ws,
    float* __restrict__ out)
{
    __shared__ Smem S;
    const int tid = threadIdx.x;
    const int lane = tid & 63;
    const int wave = tid >> 6;
    const int row0 = blockIdx.x * TILE;

    // ---- Gather + cvt into chunked XB; stage candidate tables ----
    if (tid < 512) {
        const int row = tid & 15;
        const int kq = tid >> 4;                 // 0..31 (0-15 u, 16-31 v)
        const int node = (kq < 16) ? u[row0 + row] : v[row0 + row];
        const int col = (kq & 15) * 8;
        const float4 f0 = *(const float4*)(emb + (size_t)node * EMB + col);
        const float4 f1 = *(const float4*)(emb + (size_t)node * EMB + col + 4);
        v8h hv;
        hv[0] = (_Float16)f0.x; hv[1] = (_Float16)f0.y;
        hv[2] = (_Float16)f0.z; hv[3] = (_Float16)f0.w;
        hv[4] = (_Float16)f1.x; hv[5] = (_Float16)f1.y;
        hv[6] = (_Float16)f1.z; hv[7] = (_Float16)f1.w;
        *(v8h*)&S.XB[kq * CH + row * 8] = hv;
    }
    {
        const unsigned int* base = (const unsigned int*)(ws + W_DENSE);
        if (tid < 33) *(uint4*)&S.off[tid * 4] = *(const uint4*)(base + tid * 4);
        *(uint4*)&S.ent[tid * 4] = *(const uint4*)(base + 132 + tid * 4);
    }
    __syncthreads();

    // ---- Witness 1 ----
    dense_mfma<256, 8, 64, 0, true, false>(ws + OFF_E1W1, e1_b1, S.XB, nullptr,
                                           S.H, nullptr, 0, wave, lane);
    __syncthreads();
    dense_mfma<64, 2, 64, 1, true, true>(ws + OFF_E1W2, e1_b2, S.H, nullptr,
                                         S.W12C, S.WITrm, 0, wave, lane);
    __syncthreads();

    // ---- Witness 2 ----
    dense_mfma<320, 8, 64, 0, true, false>(ws + OFF_E2W1, e2_b1, S.XB, S.W12C,
                                           S.H, nullptr, 0, wave, lane);
    __syncthreads();
    dense_mfma<64, 2, 128, 1, true, true>(ws + OFF_E2W2, e2_b2, S.H, nullptr,
                                          S.W12C + 8 * CH, S.WITrm, 64, wave, lane);
    __syncthreads();

    // ---- Witness 3 ----
    dense_mfma<384, 8, 64, 0, true, false>(ws + OFF_E3W1, e3_b1, S.XB, S.W12C + 8 * CH,
                                           S.H, nullptr, 0, wave, lane);
    __syncthreads();
    dense_mfma<64, 2, 256, 1, false, true>(ws + OFF_E3W2, e3_b2, S.H, nullptr,
                                           nullptr, S.WITrm, 192, wave, lane);
    __syncthreads();

    // ---- Tropical via exact ragged candidate pruning ----
    // wave covers o-octet; lane = (r = lane&15, cp = lane>>4). fp32 sums.
    {
        const int r = lane & 15;
        const int cp = lane >> 4;
        const _Float16* wrow = &S.WITrm[r * WITS];
        #pragma unroll
        for (int i = 0; i < 8; ++i) {
            const int o = (wave << 3) + i;
            const int beg = (int)S.off[o];
            const int end = (int)S.off[o + 1];
            float acc = 1e30f;
            for (int idx = beg + cp; idx < end; idx += 4) {
                const unsigned int cwv = S.ent[idx];
                const int j = (int)(cwv >> 16);
                const float tv = (float)__builtin_bit_cast(
                    _Float16, (unsigned short)(cwv & 0xffffu));
                acc = fminf(acc, (float)wrow[j] + tv);
            }
            acc = fminf(acc, __shfl_xor(acc, 16, 64));
            acc = fminf(acc, __shfl_xor(acc, 32, 64));
            if (cp == 0)
                S.CODE[(o >> 3) * CH + r * 8 + (o & 7)] = (_Float16)acc;
        }
    }
    __syncthreads();

    // ---- Decoder 1: CODE(128) -> H(64) relu ----
    dense_mfma<128, 4, 64, 0, true, false>(ws + OFF_DW1, dec_b1, S.CODE, nullptr,
                                           S.H, nullptr, 0, wave, lane);
    __syncthreads();

    // ---- Decoder 2: H(64) -> scalar ----
    if (tid < TILE) {
        const int r = tid;
        float s = dec_b2[0];
        const _Float16* w2 = ws + OFF_DW2;
        #pragma unroll
        for (int c = 0; c < 8; ++c) {
            const v8h hr = *(const v8h*)(&S.H[c * CH + r * 8]);
            const v8h wr = *(const v8h*)(w2 + c * 8);
            #pragma unroll
            for (int t = 0; t < 8; ++t) s += (float)hr[t] * (float)wr[t];
        }
        out[row0 + r] = s;
    }
}

extern "C" void kernel_launch(void* const* d_in, const int* in_sizes, int n_in,
                              void* d_out, int out_size, void* d_ws, size_t ws_size,
                              hipStream_t stream) {
    const int*   u      = (const int*)d_in[0];
    const int*   v      = (const int*)d_in[1];
    const float* emb    = (const float*)d_in[2];
    const float* e1_w1  = (const float*)d_in[3];
    const float* e1_b1  = (const float*)d_in[4];
    const float* e1_w2  = (const float*)d_in[5];
    const float* e1_b2  = (const float*)d_in[6];
    const float* e2_w1  = (const float*)d_in[7];
    const float* e2_b1  = (const float*)d_in[8];
    const float* e2_w2  = (const float*)d_in[9];
    const float* e2_b2  = (const float*)d_in[10];
    const float* e3_w1  = (const float*)d_in[11];
    const float* e3_b1  = (const float*)d_in[12];
    const float* e3_w2  = (const float*)d_in[13];
    const float* e3_b2  = (const float*)d_in[14];
    const float* trop_w = (const float*)d_in[15];
    const float* dec_w1 = (const float*)d_in[16];
    const float* dec_b1 = (const float*)d_in[17];
    const float* dec_w2 = (const float*)d_in[18];
    const float* dec_b2 = (const float*)d_in[19];
    float* out = (float*)d_out;
    _Float16* ws = (_Float16*)d_ws;

    prep_kernel<<<26, 1024, 0, stream>>>(
        e1_w1, e1_w2, e2_w1, e2_w2, e3_w1, e3_w2, dec_w1, dec_w2, trop_w, ws);

    tacit_fused_kernel<<<BATCH / TILE, NTHREADS, 0, stream>>>(
        u, v, emb,
        e1_b1, e1_b2, e2_b1, e2_b2, e3_b1, e3_b2, dec_b1, dec_b2,
        ws, out);
}

// Round 9
// 147.647 us; speedup vs baseline: 1.5612x; 1.0671x over previous
//
#include <hip/hip_runtime.h>
#include <hip/hip_fp16.h>
#include <math.h>

#define BATCH 8192
#define EMB 128
#define TILE 16
#define NTHREADS 1024
#define NWAVES 16
#define CH 136      // chunk stride in halves: 16 rows * 8 + 8 pad (272B; quads decollide banks)
#define WITS 450    // row-major WIT stride (halves): 900B -> 225 words (odd) -> full bank spread
#define ENT_CAP 4096

// ws half-offsets (dense fp16 weights)
#define OFF_E1W1 0        // 64x256
#define OFF_E1W2 16384    // 64x64
#define OFF_E2W1 20480    // 64x320
#define OFF_E2W2 40960    // 128x64
#define OFF_E3W1 49152    // 64x384
#define OFF_E3W2 73728    // 256x64
#define OFF_DW1  90112    // 64x128
#define OFF_DW2  98304    // 1x64
#define W_DENSE  98368
// candidate region (uint32s, based at ws + W_DENSE):
//   [0..127]   per-row packed (count<<16 | beg)
//   [131]      allocation counter (memset to 0 pre-launch)
//   [132 ...]  packed entries (j<<16 | fp16bits(T[o][j])), ragged by o

typedef __attribute__((ext_vector_type(8))) _Float16 v8h;
typedef __attribute__((ext_vector_type(4))) float v4f;

struct Smem {
    _Float16 XB[32 * CH];        // base, chunked MFMA-A layout
    _Float16 W12C[24 * CH];      // w1 chunks 0-7, w2 chunks 8-23 (chunked)
    _Float16 H[8 * CH];          // hidden, chunked
    _Float16 CODE[16 * CH];      // tropical out, chunked
    _Float16 WITrm[TILE * WITS]; // wit row-major for the gather
    unsigned int ent[ENT_CAP];
    unsigned int off[132];
};

// ---------------- prepass ----------------
// Blocks 0..24: fp32->fp16 cvt (1024-wide).
// Blocks 25..32: wave-parallel candidate build, one wave per trop row,
// slot allocation via device-scope atomicAdd (no barriers, single pass).
__global__ __launch_bounds__(1024) void prep_kernel(
    const float* __restrict__ s0, const float* __restrict__ s1,
    const float* __restrict__ s2, const float* __restrict__ s3,
    const float* __restrict__ s4, const float* __restrict__ s5,
    const float* __restrict__ s6, const float* __restrict__ s7,
    const float* __restrict__ trop, _Float16* __restrict__ ws)
{
    const int b = blockIdx.x;
    const int tid = threadIdx.x;
    if (b < 25) {
        const int idx4 = (b * 1024 + tid) * 4;
        if (idx4 >= W_DENSE) return;
        const float* src; int off;
        if      (idx4 < OFF_E1W2) { src = s0; off = OFF_E1W1; }
        else if (idx4 < OFF_E2W1) { src = s1; off = OFF_E1W2; }
        else if (idx4 < OFF_E2W2) { src = s2; off = OFF_E2W1; }
        else if (idx4 < OFF_E3W1) { src = s3; off = OFF_E2W2; }
        else if (idx4 < OFF_E3W2) { src = s4; off = OFF_E3W1; }
        else if (idx4 < OFF_DW1)  { src = s5; off = OFF_E3W2; }
        else if (idx4 < OFF_DW2)  { src = s6; off = OFF_DW1;  }
        else                      { src = s7; off = OFF_DW2;  }
        const float4 v = *(const float4*)(src + (idx4 - off));
        _Float16* dst = ws + idx4;
        dst[0] = (_Float16)v.x; dst[1] = (_Float16)v.y;
        dst[2] = (_Float16)v.z; dst[3] = (_Float16)v.w;
    } else {
        const int lane = tid & 63;
        const int wave = tid >> 6;
        const int o = (b - 25) * 16 + wave;   // 8 blocks x 16 waves = 128 rows
        if (o >= 128) return;
        unsigned int* base = (unsigned int*)(ws + W_DENSE);
        unsigned int* counter = base + 131;

        const float* row = trop + (size_t)o * 448;
        float vals[7];
        float mn = 1e30f;
        #pragma unroll
        for (int it = 0; it < 7; ++it) {
            vals[it] = row[lane + it * 64];
            mn = fminf(mn, vals[it]);
        }
        mn = fminf(mn, __shfl_xor(mn, 1, 64));
        mn = fminf(mn, __shfl_xor(mn, 2, 64));
        mn = fminf(mn, __shfl_xor(mn, 4, 64));
        mn = fminf(mn, __shfl_xor(mn, 8, 64));
        mn = fminf(mn, __shfl_xor(mn, 16, 64));
        mn = fminf(mn, __shfl_xor(mn, 32, 64));
        // wit in [0,1] (+fp16 slack) => only j with T[o,j] <= minT + 1.02
        // can win the min-plus. Exact pruning.
        const float thr = mn + 1.02f;

        unsigned long long masks[7];
        unsigned int n = 0;
        #pragma unroll
        for (int it = 0; it < 7; ++it) {
            masks[it] = __ballot(vals[it] <= thr);
            n += (unsigned)__popcll(masks[it]);
        }
        unsigned int beg = 0;
        if (lane == 0) beg = atomicAdd(counter, n);
        beg = (unsigned)__shfl((int)beg, 0, 64);
        if (lane == 0) base[o] = (n << 16) | (beg & 0xffffu);

        unsigned int done = beg;
        const unsigned long long ltmask = (1ull << lane) - 1ull;
        #pragma unroll
        for (int it = 0; it < 7; ++it) {
            const unsigned long long m = masks[it];
            if (vals[it] <= thr) {
                const unsigned int pos = done + (unsigned)__popcll(m & ltmask);
                if (pos < ENT_CAP) {
                    const unsigned short hb =
                        __builtin_bit_cast(unsigned short, (_Float16)vals[it]);
                    base[132 + pos] = ((unsigned)(lane + it * 64) << 16) | hb;
                }
            }
            done += (unsigned)__popcll(m);
        }
    }
}

// ---------------- MFMA dense layer (M=16 rows) ----------------
// D[m][o] = act(bias[o] + sum_k A[m][k]*W[o][k]). A chunked in LDS
// (A0 first STEPS0 steps, then A1); W row-major [O][K] in global.
template <int K, int STEPS0, int O, int ACT, bool CHUNKW, bool RMW>
__device__ __forceinline__ void dense_mfma(
    const _Float16* __restrict__ Wg, const float* __restrict__ bias,
    const _Float16* A0, const _Float16* A1,
    _Float16* OutC, _Float16* OutRM, int rmbase, int wave, int lane)
{
    constexpr int STEPS = K / 32;
    constexpr int NJOBS = O / 16;
    const int l15 = lane & 15;
    const int quad = lane >> 4;

    for (int nt = wave; nt < NJOBS; nt += NWAVES) {
        v4f c = {0.f, 0.f, 0.f, 0.f};
        const _Float16* wrow = Wg + (size_t)(nt * 16 + l15) * K + quad * 8;
        #pragma unroll
        for (int s = 0; s < STEPS; ++s) {
            const int g = s * 4 + quad;
            const _Float16* asrc = (s < STEPS0)
                ? (A0 + g * CH + l15 * 8)
                : (A1 + (g - STEPS0 * 4) * CH + l15 * 8);
            const v8h a = *(const v8h*)asrc;              // A[m=l15][k=quad*8+j]
            const v8h bfr = *(const v8h*)(wrow + s * 32); // B[n=l15][k=quad*8+j]
            c = __builtin_amdgcn_mfma_f32_16x16x32_f16(a, bfr, c, 0, 0, 0);
        }
        const int o = nt * 16 + l15;                      // C/D col = lane&15
        const float bs = bias[o];
        #pragma unroll
        for (int i = 0; i < 4; ++i) {                     // C/D row = quad*4+reg
            float vv = c[i] + bs;
            if (ACT == 0) vv = fmaxf(vv, 0.f);
            else          vv = 1.f / (1.f + __expf(-vv));
            const int m = quad * 4 + i;
            const _Float16 hv = (_Float16)vv;
            if (CHUNKW) OutC[(o >> 3) * CH + m * 8 + (o & 7)] = hv;
            if (RMW)    OutRM[m * WITS + rmbase + o] = hv;
        }
    }
}

// ---------------- fused forward ----------------
__global__ __launch_bounds__(NTHREADS, 8) void tacit_fused_kernel(
    const int* __restrict__ u, const int* __restrict__ v,
    const float* __restrict__ emb,
    const float* __restrict__ e1_b1, const float* __restrict__ e1_b2,
    const float* __restrict__ e2_b1, const float* __restrict__ e2_b2,
    const float* __restrict__ e3_b1, const float* __restrict__ e3_b2,
    const float* __restrict__ dec_b1, const float* __restrict__ dec_b2,
    const _Float16* __restrict__ ws,
    float* __restrict__ out)
{
    __shared__ Smem S;
    const int tid = threadIdx.x;
    const int lane = tid & 63;
    const int wave = tid >> 6;
    const int row0 = blockIdx.x * TILE;

    // ---- Gather + cvt into chunked XB; stage candidate tables ----
    if (tid < 512) {
        const int row = tid & 15;
        const int kq = tid >> 4;                 // 0..31 (0-15 u, 16-31 v)
        const int node = (kq < 16) ? u[row0 + row] : v[row0 + row];
        const int col = (kq & 15) * 8;
        const float4 f0 = *(const float4*)(emb + (size_t)node * EMB + col);
        const float4 f1 = *(const float4*)(emb + (size_t)node * EMB + col + 4);
        v8h hv;
        hv[0] = (_Float16)f0.x; hv[1] = (_Float16)f0.y;
        hv[2] = (_Float16)f0.z; hv[3] = (_Float16)f0.w;
        hv[4] = (_Float16)f1.x; hv[5] = (_Float16)f1.y;
        hv[6] = (_Float16)f1.z; hv[7] = (_Float16)f1.w;
        *(v8h*)&S.XB[kq * CH + row * 8] = hv;
    }
    {
        const unsigned int* base = (const unsigned int*)(ws + W_DENSE);
        if (tid < 33) *(uint4*)&S.off[tid * 4] = *(const uint4*)(base + tid * 4);
        *(uint4*)&S.ent[tid * 4] = *(const uint4*)(base + 132 + tid * 4);
    }
    __syncthreads();

    // ---- Witness 1 ----
    dense_mfma<256, 8, 64, 0, true, false>(ws + OFF_E1W1, e1_b1, S.XB, nullptr,
                                           S.H, nullptr, 0, wave, lane);
    __syncthreads();
    dense_mfma<64, 2, 64, 1, true, true>(ws + OFF_E1W2, e1_b2, S.H, nullptr,
                                         S.W12C, S.WITrm, 0, wave, lane);
    __syncthreads();

    // ---- Witness 2 ----
    dense_mfma<320, 8, 64, 0, true, false>(ws + OFF_E2W1, e2_b1, S.XB, S.W12C,
                                           S.H, nullptr, 0, wave, lane);
    __syncthreads();
    dense_mfma<64, 2, 128, 1, true, true>(ws + OFF_E2W2, e2_b2, S.H, nullptr,
                                          S.W12C + 8 * CH, S.WITrm, 64, wave, lane);
    __syncthreads();

    // ---- Witness 3 ----
    dense_mfma<384, 8, 64, 0, true, false>(ws + OFF_E3W1, e3_b1, S.XB, S.W12C + 8 * CH,
                                           S.H, nullptr, 0, wave, lane);
    __syncthreads();
    dense_mfma<64, 2, 256, 1, false, true>(ws + OFF_E3W2, e3_b2, S.H, nullptr,
                                           nullptr, S.WITrm, 192, wave, lane);
    __syncthreads();

    // ---- Tropical via exact ragged candidate pruning ----
    // wave covers o-octet; lane = (r = lane&15, cp = lane>>4). fp32 sums.
    {
        const int r = lane & 15;
        const int cp = lane >> 4;
        const _Float16* wrow = &S.WITrm[r * WITS];
        #pragma unroll
        for (int i = 0; i < 8; ++i) {
            const int o = (wave << 3) + i;
            const unsigned int tb = S.off[o];
            const int beg = (int)(tb & 0xffffu);
            int end = beg + (int)(tb >> 16);
            end = end < ENT_CAP ? end : ENT_CAP;
            float acc = 1e30f;
            for (int idx = beg + cp; idx < end; idx += 4) {
                const unsigned int cwv = S.ent[idx];
                const int j = (int)(cwv >> 16);
                const float tv = (float)__builtin_bit_cast(
                    _Float16, (unsigned short)(cwv & 0xffffu));
                acc = fminf(acc, (float)wrow[j] + tv);
            }
            acc = fminf(acc, __shfl_xor(acc, 16, 64));
            acc = fminf(acc, __shfl_xor(acc, 32, 64));
            if (cp == 0)
                S.CODE[(o >> 3) * CH + r * 8 + (o & 7)] = (_Float16)acc;
        }
    }
    __syncthreads();

    // ---- Decoder 1: CODE(128) -> H(64) relu ----
    dense_mfma<128, 4, 64, 0, true, false>(ws + OFF_DW1, dec_b1, S.CODE, nullptr,
                                           S.H, nullptr, 0, wave, lane);
    __syncthreads();

    // ---- Decoder 2: H(64) -> scalar ----
    if (tid < TILE) {
        const int r = tid;
        float s = dec_b2[0];
        const _Float16* w2 = ws + OFF_DW2;
        #pragma unroll
        for (int c = 0; c < 8; ++c) {
            const v8h hr = *(const v8h*)(&S.H[c * CH + r * 8]);
            const v8h wr = *(const v8h*)(w2 + c * 8);
            #pragma unroll
            for (int t = 0; t < 8; ++t) s += (float)hr[t] * (float)wr[t];
        }
        out[row0 + r] = s;
    }
}

extern "C" void kernel_launch(void* const* d_in, const int* in_sizes, int n_in,
                              void* d_out, int out_size, void* d_ws, size_t ws_size,
                              hipStream_t stream) {
    const int*   u      = (const int*)d_in[0];
    const int*   v      = (const int*)d_in[1];
    const float* emb    = (const float*)d_in[2];
    const float* e1_w1  = (const float*)d_in[3];
    const float* e1_b1  = (const float*)d_in[4];
    const float* e1_w2  = (const float*)d_in[5];
    const float* e1_b2  = (const float*)d_in[6];
    const float* e2_w1  = (const float*)d_in[7];
    const float* e2_b1  = (const float*)d_in[8];
    const float* e2_w2  = (const float*)d_in[9];
    const float* e2_b2  = (const float*)d_in[10];
    const float* e3_w1  = (const float*)d_in[11];
    const float* e3_b1  = (const float*)d_in[12];
    const float* e3_w2  = (const float*)d_in[13];
    const float* e3_b2  = (const float*)d_in[14];
    const float* trop_w = (const float*)d_in[15];
    const float* dec_w1 = (const float*)d_in[16];
    const float* dec_b1 = (const float*)d_in[17];
    const float* dec_w2 = (const float*)d_in[18];
    const float* dec_b2 = (const float*)d_in[19];
    float* out = (float*)d_out;
    _Float16* ws = (_Float16*)d_ws;

    // zero the candidate-slot allocation counter (uint at W_DENSE + 131)
    hipMemsetAsync((char*)d_ws + (size_t)W_DENSE * 2 + 131 * 4, 0, 4, stream);

    prep_kernel<<<33, 1024, 0, stream>>>(
        e1_w1, e1_w2, e2_w1, e2_w2, e3_w1, e3_w2, dec_w1, dec_w2, trop_w, ws);

    tacit_fused_kernel<<<BATCH / TILE, NTHREADS, 0, stream>>>(
        u, v, emb,
        e1_b1, e1_b2, e2_b1, e2_b2, e3_b1, e3_b2, dec_b1, dec_b2,
        ws, out);
}

// Round 10
// 145.528 us; speedup vs baseline: 1.5840x; 1.0146x over previous
//
#include <hip/hip_runtime.h>
#include <hip/hip_fp16.h>
#include <math.h>

#define BATCH 8192
#define EMB 128
#define TILE 16
#define NTHREADS 1024
#define NWAVES 16
#define CH 136      // chunk stride in halves: 16 rows * 8 + 8 pad (272B; quads decollide banks)
#define WITS 450    // row-major WIT stride (halves): 900B -> 225 words (odd) -> full bank spread
#define ENT_CAP 4096

// ws half-offsets (dense fp16 weights)
#define OFF_E1W1 0        // 64x256
#define OFF_E1W2 16384    // 64x64
#define OFF_E2W1 20480    // 64x320
#define OFF_E2W2 40960    // 128x64
#define OFF_E3W1 49152    // 64x384
#define OFF_E3W2 73728    // 256x64
#define OFF_DW1  90112    // 64x128
#define OFF_DW2  98304    // 1x64
#define W_DENSE  98368
// candidate region (uint32s, based at ws + W_DENSE):
//   [0..127]   per-row packed (count<<16 | beg)
//   [131]      allocation counter (memset to 0 pre-launch)
//   [132 ...]  packed entries (j<<16 | fp16bits(T[o][j])), ragged by o

typedef __attribute__((ext_vector_type(8))) _Float16 v8h;
typedef __attribute__((ext_vector_type(4))) float v4f;

struct Smem {
    _Float16 XB[32 * CH];        // base, chunked MFMA-A layout
    _Float16 W12C[24 * CH];      // w1 chunks 0-7, w2 chunks 8-23 (chunked)
    _Float16 H[8 * CH];          // hidden, chunked
    _Float16 CODE[16 * CH];      // tropical out, chunked
    _Float16 WITrm[TILE * WITS]; // wit row-major for the gather
    unsigned int ent[ENT_CAP];
    unsigned int off[132];
};

// ---------------- prepass ----------------
// Blocks 0..24: fp32->fp16 cvt (1024-wide).
// Blocks 25..32: wave-parallel candidate build, one wave per trop row,
// slot allocation via device-scope atomicAdd (no barriers, single pass).
__global__ __launch_bounds__(1024) void prep_kernel(
    const float* __restrict__ s0, const float* __restrict__ s1,
    const float* __restrict__ s2, const float* __restrict__ s3,
    const float* __restrict__ s4, const float* __restrict__ s5,
    const float* __restrict__ s6, const float* __restrict__ s7,
    const float* __restrict__ trop, _Float16* __restrict__ ws)
{
    const int b = blockIdx.x;
    const int tid = threadIdx.x;
    if (b < 25) {
        const int idx4 = (b * 1024 + tid) * 4;
        if (idx4 >= W_DENSE) return;
        const float* src; int off;
        if      (idx4 < OFF_E1W2) { src = s0; off = OFF_E1W1; }
        else if (idx4 < OFF_E2W1) { src = s1; off = OFF_E1W2; }
        else if (idx4 < OFF_E2W2) { src = s2; off = OFF_E2W1; }
        else if (idx4 < OFF_E3W1) { src = s3; off = OFF_E2W2; }
        else if (idx4 < OFF_E3W2) { src = s4; off = OFF_E3W1; }
        else if (idx4 < OFF_DW1)  { src = s5; off = OFF_E3W2; }
        else if (idx4 < OFF_DW2)  { src = s6; off = OFF_DW1;  }
        else                      { src = s7; off = OFF_DW2;  }
        const float4 v = *(const float4*)(src + (idx4 - off));
        _Float16* dst = ws + idx4;
        dst[0] = (_Float16)v.x; dst[1] = (_Float16)v.y;
        dst[2] = (_Float16)v.z; dst[3] = (_Float16)v.w;
    } else {
        const int lane = tid & 63;
        const int wave = tid >> 6;
        const int o = (b - 25) * 16 + wave;   // 8 blocks x 16 waves = 128 rows
        if (o >= 128) return;
        unsigned int* base = (unsigned int*)(ws + W_DENSE);
        unsigned int* counter = base + 131;

        const float* row = trop + (size_t)o * 448;
        float vals[7];
        float mn = 1e30f;
        #pragma unroll
        for (int it = 0; it < 7; ++it) {
            vals[it] = row[lane + it * 64];
            mn = fminf(mn, vals[it]);
        }
        mn = fminf(mn, __shfl_xor(mn, 1, 64));
        mn = fminf(mn, __shfl_xor(mn, 2, 64));
        mn = fminf(mn, __shfl_xor(mn, 4, 64));
        mn = fminf(mn, __shfl_xor(mn, 8, 64));
        mn = fminf(mn, __shfl_xor(mn, 16, 64));
        mn = fminf(mn, __shfl_xor(mn, 32, 64));
        // wit in [0,1] (+fp16 slack) => only j with T[o,j] <= minT + 1.02
        // can win the min-plus. Exact pruning.
        const float thr = mn + 1.02f;

        unsigned long long masks[7];
        unsigned int n = 0;
        #pragma unroll
        for (int it = 0; it < 7; ++it) {
            masks[it] = __ballot(vals[it] <= thr);
            n += (unsigned)__popcll(masks[it]);
        }
        unsigned int beg = 0;
        if (lane == 0) beg = atomicAdd(counter, n);
        beg = (unsigned)__shfl((int)beg, 0, 64);
        if (lane == 0) base[o] = (n << 16) | (beg & 0xffffu);

        unsigned int done = beg;
        const unsigned long long ltmask = (1ull << lane) - 1ull;
        #pragma unroll
        for (int it = 0; it < 7; ++it) {
            const unsigned long long m = masks[it];
            if (vals[it] <= thr) {
                const unsigned int pos = done + (unsigned)__popcll(m & ltmask);
                if (pos < ENT_CAP) {
                    const unsigned short hb =
                        __builtin_bit_cast(unsigned short, (_Float16)vals[it]);
                    base[132 + pos] = ((unsigned)(lane + it * 64) << 16) | hb;
                }
            }
            done += (unsigned)__popcll(m);
        }
    }
}

// ---------------- MFMA dense layer (M=16 rows) ----------------
// D[m][o] = act(bias[o] + sum_k A[m][k]*W[o][k]). A chunked in LDS
// (A0 first STEPS0 steps, then A1); W row-major [O][K] in global.
// Dual accumulators (STEPS is always even) halve the dependent-MFMA chain.
template <int K, int STEPS0, int O, int ACT, bool CHUNKW, bool RMW>
__device__ __forceinline__ void dense_mfma(
    const _Float16* __restrict__ Wg, const float* __restrict__ bias,
    const _Float16* A0, const _Float16* A1,
    _Float16* OutC, _Float16* OutRM, int rmbase, int wave, int lane)
{
    constexpr int STEPS = K / 32;
    static_assert(STEPS % 2 == 0, "even steps");
    constexpr int NJOBS = O / 16;
    const int l15 = lane & 15;
    const int quad = lane >> 4;

    for (int nt = wave; nt < NJOBS; nt += NWAVES) {
        v4f c0 = {0.f, 0.f, 0.f, 0.f};
        v4f c1 = {0.f, 0.f, 0.f, 0.f};
        const _Float16* wrow = Wg + (size_t)(nt * 16 + l15) * K + quad * 8;
        #pragma unroll
        for (int s = 0; s < STEPS; s += 2) {
            const int g0 = s * 4 + quad;
            const int g1 = (s + 1) * 4 + quad;
            const _Float16* a0p = (s < STEPS0)
                ? (A0 + g0 * CH + l15 * 8)
                : (A1 + (g0 - STEPS0 * 4) * CH + l15 * 8);
            const _Float16* a1p = ((s + 1) < STEPS0)
                ? (A0 + g1 * CH + l15 * 8)
                : (A1 + (g1 - STEPS0 * 4) * CH + l15 * 8);
            const v8h a0 = *(const v8h*)a0p;
            const v8h b0 = *(const v8h*)(wrow + s * 32);
            const v8h a1 = *(const v8h*)a1p;
            const v8h b1 = *(const v8h*)(wrow + (s + 1) * 32);
            c0 = __builtin_amdgcn_mfma_f32_16x16x32_f16(a0, b0, c0, 0, 0, 0);
            c1 = __builtin_amdgcn_mfma_f32_16x16x32_f16(a1, b1, c1, 0, 0, 0);
        }
        const v4f c = c0 + c1;
        const int o = nt * 16 + l15;                      // C/D col = lane&15
        const float bs = bias[o];
        #pragma unroll
        for (int i = 0; i < 4; ++i) {                     // C/D row = quad*4+reg
            float vv = c[i] + bs;
            if (ACT == 0) vv = fmaxf(vv, 0.f);
            else          vv = 1.f / (1.f + __expf(-vv));
            const int m = quad * 4 + i;
            const _Float16 hv = (_Float16)vv;
            if (CHUNKW) OutC[(o >> 3) * CH + m * 8 + (o & 7)] = hv;
            if (RMW)    OutRM[m * WITS + rmbase + o] = hv;
        }
    }
}

// ---------------- fused forward ----------------
__global__ __launch_bounds__(NTHREADS, 8) void tacit_fused_kernel(
    const int* __restrict__ u, const int* __restrict__ v,
    const float* __restrict__ emb,
    const float* __restrict__ e1_b1, const float* __restrict__ e1_b2,
    const float* __restrict__ e2_b1, const float* __restrict__ e2_b2,
    const float* __restrict__ e3_b1, const float* __restrict__ e3_b2,
    const float* __restrict__ dec_b1, const float* __restrict__ dec_b2,
    const _Float16* __restrict__ ws,
    float* __restrict__ out)
{
    __shared__ Smem S;
    const int tid = threadIdx.x;
    const int lane = tid & 63;
    const int wave = tid >> 6;
    const int row0 = blockIdx.x * TILE;

    // ---- Stage candidate tables; gather + cvt into chunked XB ----
    {
        const unsigned int* base = (const unsigned int*)(ws + W_DENSE);
        if (tid < 33) *(uint4*)&S.off[tid * 4] = *(const uint4*)(base + tid * 4);
        *(uint4*)&S.ent[tid * 4] = *(const uint4*)(base + 132 + tid * 4);
    }
    if (tid < 512) {
        const int row = tid & 15;
        const int kq = tid >> 4;                 // 0..31 (0-15 u, 16-31 v)
        const int node = (kq < 16) ? u[row0 + row] : v[row0 + row];
        const int col = (kq & 15) * 8;
        const float4 f0 = *(const float4*)(emb + (size_t)node * EMB + col);
        const float4 f1 = *(const float4*)(emb + (size_t)node * EMB + col + 4);
        v8h hv;
        hv[0] = (_Float16)f0.x; hv[1] = (_Float16)f0.y;
        hv[2] = (_Float16)f0.z; hv[3] = (_Float16)f0.w;
        hv[4] = (_Float16)f1.x; hv[5] = (_Float16)f1.y;
        hv[6] = (_Float16)f1.z; hv[7] = (_Float16)f1.w;
        *(v8h*)&S.XB[kq * CH + row * 8] = hv;
    }
    __syncthreads();

    // ---- Witness 1 ----
    dense_mfma<256, 8, 64, 0, true, false>(ws + OFF_E1W1, e1_b1, S.XB, nullptr,
                                           S.H, nullptr, 0, wave, lane);
    __syncthreads();
    dense_mfma<64, 2, 64, 1, true, true>(ws + OFF_E1W2, e1_b2, S.H, nullptr,
                                         S.W12C, S.WITrm, 0, wave, lane);
    __syncthreads();

    // ---- Witness 2 ----
    dense_mfma<320, 8, 64, 0, true, false>(ws + OFF_E2W1, e2_b1, S.XB, S.W12C,
                                           S.H, nullptr, 0, wave, lane);
    __syncthreads();
    dense_mfma<64, 2, 128, 1, true, true>(ws + OFF_E2W2, e2_b2, S.H, nullptr,
                                          S.W12C + 8 * CH, S.WITrm, 64, wave, lane);
    __syncthreads();

    // ---- Witness 3 ----
    dense_mfma<384, 8, 64, 0, true, false>(ws + OFF_E3W1, e3_b1, S.XB, S.W12C + 8 * CH,
                                           S.H, nullptr, 0, wave, lane);
    __syncthreads();
    dense_mfma<64, 2, 256, 1, false, true>(ws + OFF_E3W2, e3_b2, S.H, nullptr,
                                           nullptr, S.WITrm, 192, wave, lane);
    __syncthreads();

    // ---- Tropical via exact ragged candidate pruning, 8-way ILP ----
    // wave covers o-octet; lane = (r = lane&15, cp = lane>>4). The 8 o's
    // advance in lockstep so 8 independent ent->wrow load chains are in
    // flight per iteration (vs 1 in the serial form). fp32 mins.
    {
        const int r = lane & 15;
        const int cp = lane >> 4;
        const _Float16* wrow = &S.WITrm[r * WITS];
        float acc[8];
        int idx[8], end8[8];
        #pragma unroll
        for (int i = 0; i < 8; ++i) {
            const int o = (wave << 3) + i;
            const unsigned int tb = S.off[o];
            const int beg = (int)(tb & 0xffffu);
            int e = beg + (int)(tb >> 16);
            e = e < ENT_CAP ? e : ENT_CAP;
            idx[i] = beg + cp;
            end8[i] = e;
            acc[i] = 1e30f;
        }
        bool any = true;
        while (any) {
            any = false;
            #pragma unroll
            for (int i = 0; i < 8; ++i) {
                if (idx[i] < end8[i]) {
                    const unsigned int cwv = S.ent[idx[i]];
                    const int j = (int)(cwv >> 16);
                    const float tv = (float)__builtin_bit_cast(
                        _Float16, (unsigned short)(cwv & 0xffffu));
                    acc[i] = fminf(acc[i], (float)wrow[j] + tv);
                    idx[i] += 4;
                    any = true;
                }
            }
        }
        #pragma unroll
        for (int i = 0; i < 8; ++i) {
            float a = acc[i];
            a = fminf(a, __shfl_xor(a, 16, 64));
            a = fminf(a, __shfl_xor(a, 32, 64));
            if (cp == 0) {
                const int o = (wave << 3) + i;
                S.CODE[(o >> 3) * CH + r * 8 + (o & 7)] = (_Float16)a;
            }
        }
    }
    __syncthreads();

    // ---- Decoder 1: CODE(128) -> H(64) relu ----
    dense_mfma<128, 4, 64, 0, true, false>(ws + OFF_DW1, dec_b1, S.CODE, nullptr,
                                           S.H, nullptr, 0, wave, lane);
    __syncthreads();

    // ---- Decoder 2: H(64) -> scalar; wave 0, 4-way k-split per row ----
    if (tid < 64) {
        const int r = lane & 15;
        const int part = lane >> 4;          // chunks part and part+4
        const _Float16* w2 = ws + OFF_DW2;
        float s = 0.f;
        #pragma unroll
        for (int q = 0; q < 2; ++q) {
            const int c = part + q * 4;
            const v8h hr = *(const v8h*)(&S.H[c * CH + r * 8]);
            const v8h wr = *(const v8h*)(w2 + c * 8);
            #pragma unroll
            for (int t = 0; t < 8; ++t) s += (float)hr[t] * (float)wr[t];
        }
        s += __shfl_xor(s, 16, 64);
        s += __shfl_xor(s, 32, 64);
        if (part == 0) out[row0 + r] = s + dec_b2[0];
    }
}

extern "C" void kernel_launch(void* const* d_in, const int* in_sizes, int n_in,
                              void* d_out, int out_size, void* d_ws, size_t ws_size,
                              hipStream_t stream) {
    const int*   u      = (const int*)d_in[0];
    const int*   v      = (const int*)d_in[1];
    const float* emb    = (const float*)d_in[2];
    const float* e1_w1  = (const float*)d_in[3];
    const float* e1_b1  = (const float*)d_in[4];
    const float* e1_w2  = (const float*)d_in[5];
    const float* e1_b2  = (const float*)d_in[6];
    const float* e2_w1  = (const float*)d_in[7];
    const float* e2_b1  = (const float*)d_in[8];
    const float* e2_w2  = (const float*)d_in[9];
    const float* e2_b2  = (const float*)d_in[10];
    const float* e3_w1  = (const float*)d_in[11];
    const float* e3_b1  = (const float*)d_in[12];
    const float* e3_w2  = (const float*)d_in[13];
    const float* e3_b2  = (const float*)d_in[14];
    const float* trop_w = (const float*)d_in[15];
    const float* dec_w1 = (const float*)d_in[16];
    const float* dec_b1 = (const float*)d_in[17];
    const float* dec_w2 = (const float*)d_in[18];
    const float* dec_b2 = (const float*)d_in[19];
    float* out = (float*)d_out;
    _Float16* ws = (_Float16*)d_ws;

    // zero the candidate-slot allocation counter (uint at W_DENSE + 131)
    hipMemsetAsync((char*)d_ws + (size_t)W_DENSE * 2 + 131 * 4, 0, 4, stream);

    prep_kernel<<<33, 1024, 0, stream>>>(
        e1_w1, e1_w2, e2_w1, e2_w2, e3_w1, e3_w2, dec_w1, dec_w2, trop_w, ws);

    tacit_fused_kernel<<<BATCH / TILE, NTHREADS, 0, stream>>>(
        u, v, emb,
        e1_b1, e1_b2, e2_b1, e2_b2, e3_b1, e3_b2, dec_b1, dec_b2,
        ws, out);
}